// Round 11
// baseline (286.805 us; speedup 1.0000x reference)
//
#include <hip/hip_runtime.h>

typedef _Float16 f16;
typedef f16  f16x2  __attribute__((ext_vector_type(2)));
typedef f16  f16x8  __attribute__((ext_vector_type(8)));
typedef __fp16 h16x2 __attribute__((ext_vector_type(2)));
typedef float f32x16 __attribute__((ext_vector_type(16)));

#define B_   512
#define N_   2048
#define PADV -10000.0f

union F16x8 { f16x8 v; f16x2 h2[4]; };

__device__ __forceinline__ f16x2 pkrtz(float a, float b) {
    h16x2 r = __builtin_amdgcn_cvt_pkrtz(a, b);
    return __builtin_bit_cast(f16x2, r);
}

// wtbuf layout (f16): W0t [128 out][16 in] at 0 (natural in-order)
// Wt1/Wt2/Wt3 [128 out][128 slot] at 2048/18432/34816, slot k permuted by sigma
// to match the MFMA D-register layout (D regs ARE the next layer's B-frag).
__global__ void prep_kernel(const float* __restrict__ w0, const float* __restrict__ w1,
                            const float* __restrict__ w2, const float* __restrict__ w3,
                            f16* __restrict__ out, float* __restrict__ pooled,
                            unsigned* __restrict__ cnt)
{
    int i = blockIdx.x * 256 + threadIdx.x;   // grid 256*256 = 65536
    if (i < 2048) {
        out[i] = (f16)w0[(i & 15) * 128 + (i >> 4)];
    } else if (i < 51200) {
        int j = i - 2048;
        int l = j >> 14, r = j & 16383;
        int o = r >> 7, slot = r & 127;
        int s = slot >> 4, qq = (slot >> 3) & 1, jj = slot & 7;
        int sig = 32 * (s >> 1) + 16 * (s & 1) + 4 * qq + 8 * (jj >> 2) + (jj & 3);
        const float* w = (l == 0) ? w1 : (l == 1) ? w2 : w3;
        out[i] = (f16)w[sig * 128 + o];
    }
    pooled[i] = 0.f;   // 512*128 = 65536
    // 16 work counters (one per 32-b slot), start at 0 — all chunks dynamic
    if (blockIdx.x == 255 && threadIdx.x < 16) cnt[threadIdx.x] = 0u;
}

// swizzled byte offset into a [128 row][16 chunk] 16B-chunk weight tile
__device__ __forceinline__ int swz(int row, int chunk) {
    return row * 256 + ((chunk ^ (row & 15)) << 4);
}

__device__ __forceinline__ void gl_lds16(const void* g, void* l) {
    __builtin_amdgcn_global_load_lds(
        (const __attribute__((address_space(1))) void*)g,
        (__attribute__((address_space(3))) void*)l, 16, 0, 0);
}

// ---- fused phi (4 layers, f16 MFMA) + masked pool — resident-weight workers ----
// R10 lesson: t=2/512-thr plateaued at ~80us — 2 waves/SIMD can't hide the
// dependency latency (MfmaUtil 28% = the waves' MFMA work itself; everything
// else is exposed stall). This round: 768-thr block (12 waves), SAME 96 KB
// resident W1/W2/W3 (1 block/CU), t=1 body (32 pts/wave: acc[4]+hf[8] ~ 130
// regs) under the 170-reg cap that 3 waves/SIMD implies -> +50% concurrency.
// Work: 16 counters x 32-b slots; wave -> slot (blockIdx+wv)&15 (192 waves
// per slot); chunk = 1 b x 4 consecutive 32-pt tiles; batched probes (R9);
// next-chunk pop issued before probes (reg slack exists now, unlike R7).
// R4: pops wave-uniform (lane 0 + readfirstlane). R8: biases from GLOBAL.
__global__ __launch_bounds__(768, 3) void phi_pool_kernel(
    const float* __restrict__ x,
    const f16*  __restrict__ wtbuf,
    const float* __restrict__ pb0, const float* __restrict__ pb1,
    const float* __restrict__ pb2, const float* __restrict__ pb3,
    float* __restrict__ pooled, unsigned* __restrict__ cnt)
{
    extern __shared__ char smem[];
    char* wA = smem;             // W1 32 KB swizzled
    char* wB = smem + 32768;     // W2
    char* wC = smem + 65536;     // W3

    const int tid  = threadIdx.x;
    const int lane = tid & 63;
    const int wv   = tid >> 6;          // 0..11
    const int l31  = lane & 31;
    const int q    = lane >> 5;

    // ---- stage W1/W2/W3 once (waves 0..7, rows [16wv,16wv+16) each) ----
    if (wv < 8) {
        const f16* wsrc = wtbuf + 2048;
        #pragma unroll
        for (int i = 0; i < 4; ++i) {
            const int row   = wv * 16 + i * 4 + (lane >> 4);
            const int chunk = (lane & 15) ^ (row & 15);
            const int loff  = (wv * 16 + i * 4) * 256;   // bytes, wave-uniform
            gl_lds16(wsrc +         row * 128 + chunk * 8, wA + loff);
            gl_lds16(wsrc + 16384 + row * 128 + chunk * 8, wB + loff);
            gl_lds16(wsrc + 32768 + row * 128 + chunk * 8, wC + loff);
        }
    }

    __syncthreads();   // staging drained; last barrier in the kernel

    // bias pre-load into accumulator: acc[c][4g+e] = bias[32c + 8g + 4q + e]
    #define INIT_ACC_BIAS(pb)                                              \
        {                                                                  \
            _Pragma("unroll")                                              \
            for (int c = 0; c < 4; ++c) {                                  \
                _Pragma("unroll")                                          \
                for (int g = 0; g < 4; ++g) {                              \
                    float4 bb = *(const float4*)((pb) + 32 * c + 8 * g + 4 * q); \
                    const float* bbp = (const float*)&bb;                  \
                    _Pragma("unroll")                                      \
                    for (int e = 0; e < 4; ++e)                            \
                        acc[c][4 * g + e] = bbp[e];                        \
                }                                                          \
            }                                                              \
        }

    // epilogue: packed cvt + relu; D regs ARE the next B-frag (weights permuted)
    #define EPILOGUE()                                                     \
        {                                                                  \
            const f16x2 z2 = {(f16)0.f, (f16)0.f};                         \
            _Pragma("unroll")                                              \
            for (int s = 0; s < 8; ++s) {                                  \
                const int c = s >> 1, r0 = 8 * (s & 1);                    \
                _Pragma("unroll")                                          \
                for (int p = 0; p < 4; ++p) {                              \
                    f16x2 mm = pkrtz(                                      \
                        acc[c][r0 + 2 * p], acc[c][r0 + 2 * p + 1]);       \
                    hf[s].h2[p] = __builtin_elementwise_max(mm, z2);       \
                }                                                          \
            }                                                              \
        }

    const int slot = (blockIdx.x + wv) & 15;   // uniform 192 waves/slot
    unsigned* cp = cnt + slot;

    // ---- first pop ----
    unsigned m;
    {
        unsigned mn = 0;
        if (lane == 0) mn = atomicAdd(cp, 1u);
        m = (unsigned)__builtin_amdgcn_readfirstlane((int)mn);
    }

    #pragma unroll 1
    for (;;) {
        if (m >= 512u) break;
        const int b      = slot * 32 + (int)(m & 31);
        const int p0base = (int)(m >> 5) << 7;         // tile-group * 128 pts
        const float* xb  = x + ((size_t)b * N_ + p0base) * 16;

        // ---- prefetch next chunk id; RT hides under this chunk's work ----
        unsigned mn = 0;
        if (lane == 0) mn = atomicAdd(cp, 1u);

        // ---- batched probes: 4 consecutive 32-pt tiles of one b ----
        int pvm;
        {
            const float4 q0 = *(const float4*)(xb);
            const float4 q1 = *(const float4*)(xb + 32 * 16);
            const float4 q2 = *(const float4*)(xb + 64 * 16);
            const float4 q3 = *(const float4*)(xb + 96 * 16);
            const int v0 = !(q0.x == PADV && q0.y == PADV && q0.z == PADV && q0.w == PADV);
            const int v1 = !(q1.x == PADV && q1.y == PADV && q1.z == PADV && q1.w == PADV);
            const int v2 = !(q2.x == PADV && q2.y == PADV && q2.z == PADV && q2.w == PADV);
            const int v3 = !(q3.x == PADV && q3.y == PADV && q3.z == PADV && q3.w == PADV);
            pvm = v0 | (v1 << 1) | (v2 << 2) | (v3 << 3);
        }

        #pragma unroll 1
        for (int j = 0; j < 4; ++j) {
            if (!((pvm >> j) & 1)) continue;   // whole 32-pt tile is pad

            // ---- x loads: 1 row x 8 floats per lane ----
            const float* xp = xb + (size_t)(j * 32 + l31) * 16 + 8 * q;
            float4 a0 = ((const float4*)xp)[0];
            float4 a1 = ((const float4*)xp)[1];

            // ---- W0 A-frags, re-loaded per tile (4 KB, L2-hot; transient) ----
            f16x8 w0f[4];
            #pragma unroll
            for (int c = 0; c < 4; ++c)
                w0f[c] = *(const f16x8*)(wtbuf + (32 * c + l31) * 16 + 8 * q);

            bool vA = (a0.x != PADV) || (a0.y != PADV) || (a0.z != PADV) || (a0.w != PADV) ||
                      (a1.x != PADV) || (a1.y != PADV) || (a1.z != PADV) || (a1.w != PADV);
            unsigned long long blA = __ballot(vA);
            const unsigned mskA = (unsigned)blA | (unsigned)(blA >> 32);

            // ---- layer-0 B-frag (k = 8q+j natural order) ----
            F16x8 hf[8];
            hf[0].h2[0] = pkrtz(a0.x, a0.y);
            hf[0].h2[1] = pkrtz(a0.z, a0.w);
            hf[0].h2[2] = pkrtz(a1.x, a1.y);
            hf[0].h2[3] = pkrtz(a1.z, a1.w);

            f32x16 acc[4];

            // ---- L0: D[ch][pt], K=16 ----
            INIT_ACC_BIAS(pb0);
            #pragma unroll
            for (int c = 0; c < 4; ++c)
                acc[c] = __builtin_amdgcn_mfma_f32_32x32x16_f16(w0f[c], hf[0].v, acc[c], 0, 0, 0);
            EPILOGUE();

            // ---- L1: A = W1 from wA ----
            INIT_ACC_BIAS(pb1);
            #pragma unroll
            for (int s = 0; s < 8; ++s) {
                f16x8 wf[4];
                #pragma unroll
                for (int c = 0; c < 4; ++c)
                    wf[c] = *(const f16x8*)(wA + swz(32 * c + l31, 2 * s + q));
                #pragma unroll
                for (int c = 0; c < 4; ++c)
                    acc[c] = __builtin_amdgcn_mfma_f32_32x32x16_f16(wf[c], hf[s].v, acc[c], 0, 0, 0);
            }
            EPILOGUE();

            // ---- L2: A = W2 from wB ----
            INIT_ACC_BIAS(pb2);
            #pragma unroll
            for (int s = 0; s < 8; ++s) {
                f16x8 wf[4];
                #pragma unroll
                for (int c = 0; c < 4; ++c)
                    wf[c] = *(const f16x8*)(wB + swz(32 * c + l31, 2 * s + q));
                #pragma unroll
                for (int c = 0; c < 4; ++c)
                    acc[c] = __builtin_amdgcn_mfma_f32_32x32x16_f16(wf[c], hf[s].v, acc[c], 0, 0, 0);
            }
            EPILOGUE();

            // ---- L3: swapped orientation D[pt][ch]; b3 broadcast along rows ----
            {
                float bl3[4];
                #pragma unroll
                for (int c = 0; c < 4; ++c) bl3[c] = pb3[32 * c + l31];  // transient
                #pragma unroll
                for (int c = 0; c < 4; ++c)
                    #pragma unroll
                    for (int r = 0; r < 16; ++r) acc[c][r] = bl3[c];
            }
            #pragma unroll
            for (int s = 0; s < 8; ++s) {
                f16x8 wf[4];
                #pragma unroll
                for (int c = 0; c < 4; ++c)
                    wf[c] = *(const f16x8*)(wC + swz(32 * c + l31, 2 * s + q));
                #pragma unroll
                for (int c = 0; c < 4; ++c)
                    acc[c] = __builtin_amdgcn_mfma_f32_32x32x16_f16(hf[s].v, wf[c], acc[c], 0, 0, 0);
            }

            // ---- pool: lane owns ch = 32c + l31; rows are pts; masked select ----
            #pragma unroll
            for (int c = 0; c < 4; ++c) {
                float s0 = 0.f;
                #pragma unroll
                for (int r = 0; r < 16; ++r) {
                    const int ptl = 4 * q + (r & 3) + 8 * (r >> 2);
                    float v = fmaxf(acc[c][r], 0.f);
                    s0 += ((mskA >> ptl) & 1u) ? v : 0.f;   // select, NaN-safe
                }
                s0 += __shfl_xor(s0, 32);   // combine q halves (same ch, disjoint pt rows)
                if (q == 0) atomicAdd(&pooled[b * 128 + 32 * c + l31], s0);
            }
        }

        m = (unsigned)__builtin_amdgcn_readfirstlane((int)mn);
    }
}

// ---- rho: fp32 MLP on pooled [512][128] -> out [512] ----
__global__ __launch_bounds__(128) void rho_kernel(
    const float* __restrict__ pooled,
    const float* __restrict__ w0, const float* __restrict__ b0,
    const float* __restrict__ w1, const float* __restrict__ b1,
    const float* __restrict__ w2, const float* __restrict__ b2,
    const float* __restrict__ w3, const float* __restrict__ b3,
    float* __restrict__ out)
{
    __shared__ float buf[2][128];
    __shared__ float red[2];
    const int b = blockIdx.x, t = threadIdx.x;
    buf[0][t] = pooled[b * 128 + t];
    __syncthreads();
    const float* ws3[3] = {w0, w1, w2};
    const float* bs3[3] = {b0, b1, b2};
    int cur = 0;
    #pragma unroll 1
    for (int l = 0; l < 3; ++l) {
        float acc = bs3[l][t];
        const float* w = ws3[l];
        #pragma unroll 8
        for (int k = 0; k < 128; ++k)
            acc = fmaf(buf[cur][k], w[k * 128 + t], acc);
        buf[cur ^ 1][t] = fmaxf(acc, 0.f);
        cur ^= 1;
        __syncthreads();
    }
    float v = buf[cur][t] * w3[t];
    #pragma unroll
    for (int off = 32; off > 0; off >>= 1)
        v += __shfl_down(v, off, 64);
    if ((t & 63) == 0) red[t >> 6] = v;
    __syncthreads();
    if (t == 0) out[b] = red[0] + red[1] + b3[0];
}

extern "C" void kernel_launch(void* const* d_in, const int* in_sizes, int n_in,
                              void* d_out, int out_size, void* d_ws, size_t ws_size,
                              hipStream_t stream)
{
    (void)in_sizes; (void)n_in; (void)out_size; (void)ws_size;
    const float* x      = (const float*)d_in[0];
    const float* phi_w0 = (const float*)d_in[1];
    const float* phi_b0 = (const float*)d_in[2];
    const float* phi_w1 = (const float*)d_in[3];
    const float* phi_b1 = (const float*)d_in[4];
    const float* phi_w2 = (const float*)d_in[5];
    const float* phi_b2 = (const float*)d_in[6];
    const float* phi_w3 = (const float*)d_in[7];
    const float* phi_b3 = (const float*)d_in[8];
    const float* rho_w0 = (const float*)d_in[9];
    const float* rho_b0 = (const float*)d_in[10];
    const float* rho_w1 = (const float*)d_in[11];
    const float* rho_b1 = (const float*)d_in[12];
    const float* rho_w2 = (const float*)d_in[13];
    const float* rho_b2 = (const float*)d_in[14];
    const float* rho_w3 = (const float*)d_in[15];
    const float* rho_b3 = (const float*)d_in[16];

    float*    pooled = (float*)d_ws;                        // 512*128*4 = 262144 B
    f16*      wtbuf  = (f16*)((char*)d_ws + 262144);        // 51200 f16 = 102400 B
    unsigned* cnt    = (unsigned*)((char*)d_ws + 364544);   // 16 * 4 B work counters

    static int smem_set = 0;
    if (!smem_set) {
        hipFuncSetAttribute((const void*)phi_pool_kernel,
                            hipFuncAttributeMaxDynamicSharedMemorySize, 98304);
        smem_set = 1;
    }

    prep_kernel<<<256, 256, 0, stream>>>(phi_w0, phi_w1, phi_w2, phi_w3, wtbuf, pooled, cnt);
    phi_pool_kernel<<<256, 768, 98304, stream>>>(x, wtbuf, phi_b0, phi_b1, phi_b2, phi_b3,
                                                 pooled, cnt);
    rho_kernel<<<B_, 128, 0, stream>>>(pooled, rho_w0, rho_b0, rho_w1, rho_b1,
                                       rho_w2, rho_b2, rho_w3, rho_b3, (float*)d_out);
}

// Round 15
// 200.843 us; speedup vs baseline: 1.4280x; 1.4280x over previous
//
#include <hip/hip_runtime.h>

typedef _Float16 f16;
typedef f16  f16x2  __attribute__((ext_vector_type(2)));
typedef f16  f16x8  __attribute__((ext_vector_type(8)));
typedef __fp16 h16x2 __attribute__((ext_vector_type(2)));
typedef float f32x16 __attribute__((ext_vector_type(16)));

#define B_   512
#define N_   2048
#define PADV -10000.0f

union F16x8 { f16x8 v; f16x2 h2[4]; };

__device__ __forceinline__ f16x2 pkrtz(float a, float b) {
    h16x2 r = __builtin_amdgcn_cvt_pkrtz(a, b);
    return __builtin_bit_cast(f16x2, r);
}

// wtbuf layout (f16): W0t [128 out][16 in] at 0 (natural in-order)
// Wt1/Wt2/Wt3 [128 out][128 slot] at 2048/18432/34816, slot k permuted by sigma
// to match the MFMA D-register layout (D regs ARE the next layer's B-frag).
__global__ void prep_kernel(const float* __restrict__ w0, const float* __restrict__ w1,
                            const float* __restrict__ w2, const float* __restrict__ w3,
                            f16* __restrict__ out, float* __restrict__ pooled,
                            unsigned* __restrict__ cnt)
{
    int i = blockIdx.x * 256 + threadIdx.x;   // grid 256*256 = 65536
    if (i < 2048) {
        out[i] = (f16)w0[(i & 15) * 128 + (i >> 4)];
    } else if (i < 51200) {
        int j = i - 2048;
        int l = j >> 14, r = j & 16383;
        int o = r >> 7, slot = r & 127;
        int s = slot >> 4, qq = (slot >> 3) & 1, jj = slot & 7;
        int sig = 32 * (s >> 1) + 16 * (s & 1) + 4 * qq + 8 * (jj >> 2) + (jj & 3);
        const float* w = (l == 0) ? w1 : (l == 1) ? w2 : w3;
        out[i] = (f16)w[sig * 128 + o];
    }
    pooled[i] = 0.f;   // 512*128 = 65536
    // work counters: 8 slots, static chunks 0..255 pre-consumed
    if (blockIdx.x == 255 && threadIdx.x < 8) cnt[threadIdx.x] = 256u;
}

// swizzled byte offset into a [128 row][16 chunk] 16B-chunk weight tile
__device__ __forceinline__ int swz(int row, int chunk) {
    return row * 256 + ((chunk ^ (row & 15)) << 4);
}

__device__ __forceinline__ void gl_lds16(const void* g, void* l) {
    __builtin_amdgcn_global_load_lds(
        (const __attribute__((address_space(1))) void*)g,
        (__attribute__((address_space(3))) void*)l, 16, 0, 0);
}

// ---- fused phi (4 layers, f16 MFMA) + masked pool — resident-weight workers ----
// SESSION-BEST STRUCTURE (measured R10: 80.7us phi / 201.6us total):
// W1/W2/W3 in 96 KB dynamic LDS for the kernel lifetime (staged once, ONE
// barrier). Wave-slot wv pops chunks of 4 b's x 1 tile from cnt[wv]; first
// chunk static (=blockIdx). Batched probes per chunk. No barriers in loop.
// R4: pop must be wave-uniform (lane 0 + readfirstlane).
// R5/R7: hard 256-reg cap at 512 thr — nothing new lives across the body
//        (w0f/bias re-loaded per tile as transients).
// R8: dynamic stealing > static schedule; biases from GLOBAL beat bias-LDS.
// R11: t=1 @ 3 waves/SIMD regressed 2x — t=2 chain amortization wins.
// R12-14: T5 setprio variant untested (3x infra failures) — reverted to
//         the bit-identical measured best per the R13 decision rule.
__global__ __launch_bounds__(512, 2) void phi_pool_kernel(
    const float* __restrict__ x,
    const f16*  __restrict__ wtbuf,
    const float* __restrict__ pb0, const float* __restrict__ pb1,
    const float* __restrict__ pb2, const float* __restrict__ pb3,
    float* __restrict__ pooled, unsigned* __restrict__ cnt)
{
    extern __shared__ char smem[];
    char* wA = smem;             // W1 32 KB swizzled
    char* wB = smem + 32768;     // W2
    char* wC = smem + 65536;     // W3

    const int tid  = threadIdx.x;
    const int lane = tid & 63;
    const int wv   = tid >> 6;          // 0..7
    const int l31  = lane & 31;
    const int q    = lane >> 5;

    // ---- stage W1/W2/W3 once: wave wv stages rows [16wv, 16wv+16) of each ----
    {
        const f16* wsrc = wtbuf + 2048;
        #pragma unroll
        for (int i = 0; i < 4; ++i) {
            const int row   = wv * 16 + i * 4 + (lane >> 4);
            const int chunk = (lane & 15) ^ (row & 15);
            const int loff  = (wv * 16 + i * 4) * 256;   // bytes, wave-uniform
            gl_lds16(wsrc +         row * 128 + chunk * 8, wA + loff);
            gl_lds16(wsrc + 16384 + row * 128 + chunk * 8, wB + loff);
            gl_lds16(wsrc + 32768 + row * 128 + chunk * 8, wC + loff);
        }
    }

    __syncthreads();   // staging drained; last barrier in the kernel

    // bias pre-load into accumulator: acc[t][c][4g+e] = bias[32c + 8g + 4q + e]
    #define INIT_ACC_BIAS(pb)                                              \
        {                                                                  \
            _Pragma("unroll")                                              \
            for (int c = 0; c < 4; ++c) {                                  \
                _Pragma("unroll")                                          \
                for (int g = 0; g < 4; ++g) {                              \
                    float4 bb = *(const float4*)((pb) + 32 * c + 8 * g + 4 * q); \
                    const float* bbp = (const float*)&bb;                  \
                    _Pragma("unroll")                                      \
                    for (int e = 0; e < 4; ++e) {                          \
                        acc[0][c][4 * g + e] = bbp[e];                     \
                        acc[1][c][4 * g + e] = bbp[e];                     \
                    }                                                      \
                }                                                          \
            }                                                              \
        }

    // epilogue: packed cvt + relu; D regs ARE the next B-frag (weights permuted)
    #define EPILOGUE()                                                     \
        {                                                                  \
            const f16x2 z2 = {(f16)0.f, (f16)0.f};                         \
            _Pragma("unroll")                                              \
            for (int t = 0; t < 2; ++t) {                                  \
                _Pragma("unroll")                                          \
                for (int s = 0; s < 8; ++s) {                              \
                    const int c = s >> 1, r0 = 8 * (s & 1);                \
                    _Pragma("unroll")                                      \
                    for (int p = 0; p < 4; ++p) {                          \
                        f16x2 mm = pkrtz(                                  \
                            acc[t][c][r0 + 2 * p], acc[t][c][r0 + 2 * p + 1]); \
                        hf[t][s].h2[p] = __builtin_elementwise_max(mm, z2); \
                    }                                                      \
                }                                                          \
            }                                                              \
        }

    unsigned m = blockIdx.x;            // static first chunk (0..255)
    unsigned* cp = cnt + wv;            // this wave-slot's counter

    #pragma unroll 1
    for (;;) {
        const int t64 = (int)(m & 31) << 6;        // tile point base (0..1984)
        const int db0 = (int)((m >> 5) << 2);      // 4 consecutive b's
        const int b0  = (wv << 6) + db0;

        // ---- batched probes: 4 independent loads, collapse to a 4-bit mask ----
        int pvm;
        {
            const float* xq = x + ((size_t)b0 * N_ + t64) * 16;
            const float4 p0 = *(const float4*)(xq);
            const float4 p1 = *(const float4*)(xq + (size_t)N_ * 16);
            const float4 p2 = *(const float4*)(xq + (size_t)N_ * 32);
            const float4 p3 = *(const float4*)(xq + (size_t)N_ * 48);
            const int v0 = !(p0.x == PADV && p0.y == PADV && p0.z == PADV && p0.w == PADV);
            const int v1 = !(p1.x == PADV && p1.y == PADV && p1.z == PADV && p1.w == PADV);
            const int v2 = !(p2.x == PADV && p2.y == PADV && p2.z == PADV && p2.w == PADV);
            const int v3 = !(p3.x == PADV && p3.y == PADV && p3.z == PADV && p3.w == PADV);
            pvm = v0 | (v1 << 1) | (v2 << 2) | (v3 << 3);
        }

        #pragma unroll 1
        for (int k = 0; k < 4; ++k) {
            if (!((pvm >> k) & 1)) continue;        // whole 64-pt tile is pad
            const int b = b0 + k;
            const float* xr = x + ((size_t)b * N_ + t64) * 16;

            // ---- x loads: 2 rows x 8 floats per lane ----
            const float* xp = xr + l31 * 16 + 8 * q;
            float4 a0 = ((const float4*)xp)[0];
            float4 a1 = ((const float4*)xp)[1];
            float4 c0 = ((const float4*)(xp + 512))[0];   // +32 rows
            float4 c1 = ((const float4*)(xp + 512))[1];

            // ---- W0 A-frags, re-loaded per tile (4 KB, L2-hot; transient) ----
            f16x8 w0f[4];
            #pragma unroll
            for (int c = 0; c < 4; ++c)
                w0f[c] = *(const f16x8*)(wtbuf + (32 * c + l31) * 16 + 8 * q);

            bool vA = (a0.x != PADV) || (a0.y != PADV) || (a0.z != PADV) || (a0.w != PADV) ||
                      (a1.x != PADV) || (a1.y != PADV) || (a1.z != PADV) || (a1.w != PADV);
            bool vB = (c0.x != PADV) || (c0.y != PADV) || (c0.z != PADV) || (c0.w != PADV) ||
                      (c1.x != PADV) || (c1.y != PADV) || (c1.z != PADV) || (c1.w != PADV);
            unsigned long long blA = __ballot(vA), blB = __ballot(vB);
            const unsigned mskA = (unsigned)blA | (unsigned)(blA >> 32);
            const unsigned mskB = (unsigned)blB | (unsigned)(blB >> 32);

            // ---- layer-0 B-frags (k = 8q+j natural order) ----
            F16x8 hf[2][8];
            hf[0][0].h2[0] = pkrtz(a0.x, a0.y);
            hf[0][0].h2[1] = pkrtz(a0.z, a0.w);
            hf[0][0].h2[2] = pkrtz(a1.x, a1.y);
            hf[0][0].h2[3] = pkrtz(a1.z, a1.w);
            hf[1][0].h2[0] = pkrtz(c0.x, c0.y);
            hf[1][0].h2[1] = pkrtz(c0.z, c0.w);
            hf[1][0].h2[2] = pkrtz(c1.x, c1.y);
            hf[1][0].h2[3] = pkrtz(c1.z, c1.w);

            f32x16 acc[2][4];

            // ---- L0: D[ch][pt], K=16 ----
            INIT_ACC_BIAS(pb0);
            #pragma unroll
            for (int c = 0; c < 4; ++c) {
                acc[0][c] = __builtin_amdgcn_mfma_f32_32x32x16_f16(w0f[c], hf[0][0].v, acc[0][c], 0, 0, 0);
                acc[1][c] = __builtin_amdgcn_mfma_f32_32x32x16_f16(w0f[c], hf[1][0].v, acc[1][c], 0, 0, 0);
            }
            EPILOGUE();

            // ---- L1: A = W1 from wA ----
            INIT_ACC_BIAS(pb1);
            #pragma unroll
            for (int s = 0; s < 8; ++s) {
                f16x8 wf[4];
                #pragma unroll
                for (int c = 0; c < 4; ++c)
                    wf[c] = *(const f16x8*)(wA + swz(32 * c + l31, 2 * s + q));
                #pragma unroll
                for (int c = 0; c < 4; ++c) {
                    acc[0][c] = __builtin_amdgcn_mfma_f32_32x32x16_f16(wf[c], hf[0][s].v, acc[0][c], 0, 0, 0);
                    acc[1][c] = __builtin_amdgcn_mfma_f32_32x32x16_f16(wf[c], hf[1][s].v, acc[1][c], 0, 0, 0);
                }
            }
            EPILOGUE();

            // ---- L2: A = W2 from wB ----
            INIT_ACC_BIAS(pb2);
            #pragma unroll
            for (int s = 0; s < 8; ++s) {
                f16x8 wf[4];
                #pragma unroll
                for (int c = 0; c < 4; ++c)
                    wf[c] = *(const f16x8*)(wB + swz(32 * c + l31, 2 * s + q));
                #pragma unroll
                for (int c = 0; c < 4; ++c) {
                    acc[0][c] = __builtin_amdgcn_mfma_f32_32x32x16_f16(wf[c], hf[0][s].v, acc[0][c], 0, 0, 0);
                    acc[1][c] = __builtin_amdgcn_mfma_f32_32x32x16_f16(wf[c], hf[1][s].v, acc[1][c], 0, 0, 0);
                }
            }
            EPILOGUE();

            // ---- L3: swapped orientation D[pt][ch]; b3 broadcast along rows ----
            {
                float bl3[4];
                #pragma unroll
                for (int c = 0; c < 4; ++c) bl3[c] = pb3[32 * c + l31];  // transient
                #pragma unroll
                for (int t = 0; t < 2; ++t)
                    #pragma unroll
                    for (int c = 0; c < 4; ++c)
                        #pragma unroll
                        for (int r = 0; r < 16; ++r) acc[t][c][r] = bl3[c];
            }
            #pragma unroll
            for (int s = 0; s < 8; ++s) {
                f16x8 wf[4];
                #pragma unroll
                for (int c = 0; c < 4; ++c)
                    wf[c] = *(const f16x8*)(wC + swz(32 * c + l31, 2 * s + q));
                #pragma unroll
                for (int c = 0; c < 4; ++c) {
                    acc[0][c] = __builtin_amdgcn_mfma_f32_32x32x16_f16(hf[0][s].v, wf[c], acc[0][c], 0, 0, 0);
                    acc[1][c] = __builtin_amdgcn_mfma_f32_32x32x16_f16(hf[1][s].v, wf[c], acc[1][c], 0, 0, 0);
                }
            }

            // ---- pool: lane owns ch = 32c + l31; rows are pts; masked select ----
            #pragma unroll
            for (int c = 0; c < 4; ++c) {
                float s0 = 0.f;
                #pragma unroll
                for (int t = 0; t < 2; ++t) {
                    const unsigned msk = t ? mskB : mskA;
                    #pragma unroll
                    for (int r = 0; r < 16; ++r) {
                        const int ptl = 4 * q + (r & 3) + 8 * (r >> 2);
                        float v = fmaxf(acc[t][c][r], 0.f);
                        s0 += ((msk >> ptl) & 1u) ? v : 0.f;   // select, NaN-safe
                    }
                }
                s0 += __shfl_xor(s0, 32);
                if (q == 0) atomicAdd(&pooled[b * 128 + 32 * c + l31], s0);
            }
        }
        // ---- wave-uniform pop: lane 0 increments, broadcast to all lanes ----
        unsigned mn = 0;
        if (lane == 0) mn = atomicAdd(cp, 1u);
        m = (unsigned)__builtin_amdgcn_readfirstlane((int)mn);
        if (m >= 512u) break;
    }
}

// ---- rho: fp32 MLP on pooled [512][128] -> out [512] ----
__global__ __launch_bounds__(128) void rho_kernel(
    const float* __restrict__ pooled,
    const float* __restrict__ w0, const float* __restrict__ b0,
    const float* __restrict__ w1, const float* __restrict__ b1,
    const float* __restrict__ w2, const float* __restrict__ b2,
    const float* __restrict__ w3, const float* __restrict__ b3,
    float* __restrict__ out)
{
    __shared__ float buf[2][128];
    __shared__ float red[2];
    const int b = blockIdx.x, t = threadIdx.x;
    buf[0][t] = pooled[b * 128 + t];
    __syncthreads();
    const float* ws3[3] = {w0, w1, w2};
    const float* bs3[3] = {b0, b1, b2};
    int cur = 0;
    #pragma unroll 1
    for (int l = 0; l < 3; ++l) {
        float acc = bs3[l][t];
        const float* w = ws3[l];
        #pragma unroll 8
        for (int k = 0; k < 128; ++k)
            acc = fmaf(buf[cur][k], w[k * 128 + t], acc);
        buf[cur ^ 1][t] = fmaxf(acc, 0.f);
        cur ^= 1;
        __syncthreads();
    }
    float v = buf[cur][t] * w3[t];
    #pragma unroll
    for (int off = 32; off > 0; off >>= 1)
        v += __shfl_down(v, off, 64);
    if ((t & 63) == 0) red[t >> 6] = v;
    __syncthreads();
    if (t == 0) out[b] = red[0] + red[1] + b3[0];
}

extern "C" void kernel_launch(void* const* d_in, const int* in_sizes, int n_in,
                              void* d_out, int out_size, void* d_ws, size_t ws_size,
                              hipStream_t stream)
{
    (void)in_sizes; (void)n_in; (void)out_size; (void)ws_size;
    const float* x      = (const float*)d_in[0];
    const float* phi_w0 = (const float*)d_in[1];
    const float* phi_b0 = (const float*)d_in[2];
    const float* phi_w1 = (const float*)d_in[3];
    const float* phi_b1 = (const float*)d_in[4];
    const float* phi_w2 = (const float*)d_in[5];
    const float* phi_b2 = (const float*)d_in[6];
    const float* phi_w3 = (const float*)d_in[7];
    const float* phi_b3 = (const float*)d_in[8];
    const float* rho_w0 = (const float*)d_in[9];
    const float* rho_b0 = (const float*)d_in[10];
    const float* rho_w1 = (const float*)d_in[11];
    const float* rho_b1 = (const float*)d_in[12];
    const float* rho_w2 = (const float*)d_in[13];
    const float* rho_b2 = (const float*)d_in[14];
    const float* rho_w3 = (const float*)d_in[15];
    const float* rho_b3 = (const float*)d_in[16];

    float*    pooled = (float*)d_ws;                        // 512*128*4 = 262144 B
    f16*      wtbuf  = (f16*)((char*)d_ws + 262144);        // 51200 f16 = 102400 B
    unsigned* cnt    = (unsigned*)((char*)d_ws + 364544);   // 8 * 4 B work counters

    static int smem_set = 0;
    if (!smem_set) {
        hipFuncSetAttribute((const void*)phi_pool_kernel,
                            hipFuncAttributeMaxDynamicSharedMemorySize, 98304);
        smem_set = 1;
    }

    prep_kernel<<<256, 256, 0, stream>>>(phi_w0, phi_w1, phi_w2, phi_w3, wtbuf, pooled, cnt);
    phi_pool_kernel<<<256, 512, 98304, stream>>>(x, wtbuf, phi_b0, phi_b1, phi_b2, phi_b3,
                                                 pooled, cnt);
    rho_kernel<<<B_, 128, 0, stream>>>(pooled, rho_w0, rho_b0, rho_w1, rho_b1,
                                       rho_w2, rho_b2, rho_w3, rho_b3, (float*)d_out);
}

// Round 16
// 200.703 us; speedup vs baseline: 1.4290x; 1.0007x over previous
//
#include <hip/hip_runtime.h>

typedef _Float16 f16;
typedef f16  f16x2  __attribute__((ext_vector_type(2)));
typedef f16  f16x8  __attribute__((ext_vector_type(8)));
typedef __fp16 h16x2 __attribute__((ext_vector_type(2)));
typedef float f32x16 __attribute__((ext_vector_type(16)));

#define B_   512
#define N_   2048
#define PADV -10000.0f

union F16x8 { f16x8 v; f16x2 h2[4]; };

__device__ __forceinline__ f16x2 pkrtz(float a, float b) {
    h16x2 r = __builtin_amdgcn_cvt_pkrtz(a, b);
    return __builtin_bit_cast(f16x2, r);
}

// wtbuf layout (f16): W0t [128 out][16 in] at 0 (natural in-order)
// Wt1/Wt2/Wt3 [128 out][128 slot] at 2048/18432/34816, slot k permuted by sigma
// to match the MFMA D-register layout (D regs ARE the next layer's B-frag).
__global__ void prep_kernel(const float* __restrict__ w0, const float* __restrict__ w1,
                            const float* __restrict__ w2, const float* __restrict__ w3,
                            f16* __restrict__ out, float* __restrict__ pooled,
                            unsigned* __restrict__ cnt)
{
    int i = blockIdx.x * 256 + threadIdx.x;   // grid 256*256 = 65536
    if (i < 2048) {
        out[i] = (f16)w0[(i & 15) * 128 + (i >> 4)];
    } else if (i < 51200) {
        int j = i - 2048;
        int l = j >> 14, r = j & 16383;
        int o = r >> 7, slot = r & 127;
        int s = slot >> 4, qq = (slot >> 3) & 1, jj = slot & 7;
        int sig = 32 * (s >> 1) + 16 * (s & 1) + 4 * qq + 8 * (jj >> 2) + (jj & 3);
        const float* w = (l == 0) ? w1 : (l == 1) ? w2 : w3;
        out[i] = (f16)w[sig * 128 + o];
    }
    pooled[i] = 0.f;   // 512*128 = 65536
    // work counters: 8 slots, static chunks 0..255 pre-consumed
    if (blockIdx.x == 255 && threadIdx.x < 8) cnt[threadIdx.x] = 256u;
}

// swizzled byte offset into a [128 row][16 chunk] 16B-chunk weight tile
__device__ __forceinline__ int swz(int row, int chunk) {
    return row * 256 + ((chunk ^ (row & 15)) << 4);
}

__device__ __forceinline__ void gl_lds16(const void* g, void* l) {
    __builtin_amdgcn_global_load_lds(
        (const __attribute__((address_space(1))) void*)g,
        (__attribute__((address_space(3))) void*)l, 16, 0, 0);
}

// ---- fused phi (4 layers, f16 MFMA) + masked pool — resident-weight workers ----
// SESSION-BEST STRUCTURE (measured twice: 201.6us / 200.8us total; phi
// 80.7-97.9us across runs — run-to-run clock variance ±10% on identical
// binary): W1/W2/W3 in 96 KB dynamic LDS for the kernel lifetime (staged
// once, ONE barrier). Wave-slot wv pops chunks of 4 b's x 1 tile from
// cnt[wv]; first chunk static (=blockIdx). Batched probes. No loop barriers.
// R4: pop must be wave-uniform (lane 0 + readfirstlane).
// R5/R7: hard 256-reg cap at 512 thr — nothing new lives across the body
//        (w0f/bias re-loaded per tile as transients).
// R8: dynamic stealing > static schedule; biases from GLOBAL beat bias-LDS.
// R11: t=1 @ 3 waves/SIMD regressed 2x — t=2 chain amortization wins.
// R15: remaining levers (<10% predicted) are below the measured noise
//      floor; structure space exhausted under the 512-reg/lane file.
__global__ __launch_bounds__(512, 2) void phi_pool_kernel(
    const float* __restrict__ x,
    const f16*  __restrict__ wtbuf,
    const float* __restrict__ pb0, const float* __restrict__ pb1,
    const float* __restrict__ pb2, const float* __restrict__ pb3,
    float* __restrict__ pooled, unsigned* __restrict__ cnt)
{
    extern __shared__ char smem[];
    char* wA = smem;             // W1 32 KB swizzled
    char* wB = smem + 32768;     // W2
    char* wC = smem + 65536;     // W3

    const int tid  = threadIdx.x;
    const int lane = tid & 63;
    const int wv   = tid >> 6;          // 0..7
    const int l31  = lane & 31;
    const int q    = lane >> 5;

    // ---- stage W1/W2/W3 once: wave wv stages rows [16wv, 16wv+16) of each ----
    {
        const f16* wsrc = wtbuf + 2048;
        #pragma unroll
        for (int i = 0; i < 4; ++i) {
            const int row   = wv * 16 + i * 4 + (lane >> 4);
            const int chunk = (lane & 15) ^ (row & 15);
            const int loff  = (wv * 16 + i * 4) * 256;   // bytes, wave-uniform
            gl_lds16(wsrc +         row * 128 + chunk * 8, wA + loff);
            gl_lds16(wsrc + 16384 + row * 128 + chunk * 8, wB + loff);
            gl_lds16(wsrc + 32768 + row * 128 + chunk * 8, wC + loff);
        }
    }

    __syncthreads();   // staging drained; last barrier in the kernel

    // bias pre-load into accumulator: acc[t][c][4g+e] = bias[32c + 8g + 4q + e]
    #define INIT_ACC_BIAS(pb)                                              \
        {                                                                  \
            _Pragma("unroll")                                              \
            for (int c = 0; c < 4; ++c) {                                  \
                _Pragma("unroll")                                          \
                for (int g = 0; g < 4; ++g) {                              \
                    float4 bb = *(const float4*)((pb) + 32 * c + 8 * g + 4 * q); \
                    const float* bbp = (const float*)&bb;                  \
                    _Pragma("unroll")                                      \
                    for (int e = 0; e < 4; ++e) {                          \
                        acc[0][c][4 * g + e] = bbp[e];                     \
                        acc[1][c][4 * g + e] = bbp[e];                     \
                    }                                                      \
                }                                                          \
            }                                                              \
        }

    // epilogue: packed cvt + relu; D regs ARE the next B-frag (weights permuted)
    #define EPILOGUE()                                                     \
        {                                                                  \
            const f16x2 z2 = {(f16)0.f, (f16)0.f};                         \
            _Pragma("unroll")                                              \
            for (int t = 0; t < 2; ++t) {                                  \
                _Pragma("unroll")                                          \
                for (int s = 0; s < 8; ++s) {                              \
                    const int c = s >> 1, r0 = 8 * (s & 1);                \
                    _Pragma("unroll")                                      \
                    for (int p = 0; p < 4; ++p) {                          \
                        f16x2 mm = pkrtz(                                  \
                            acc[t][c][r0 + 2 * p], acc[t][c][r0 + 2 * p + 1]); \
                        hf[t][s].h2[p] = __builtin_elementwise_max(mm, z2); \
                    }                                                      \
                }                                                          \
            }                                                              \
        }

    unsigned m = blockIdx.x;            // static first chunk (0..255)
    unsigned* cp = cnt + wv;            // this wave-slot's counter

    #pragma unroll 1
    for (;;) {
        const int t64 = (int)(m & 31) << 6;        // tile point base (0..1984)
        const int db0 = (int)((m >> 5) << 2);      // 4 consecutive b's
        const int b0  = (wv << 6) + db0;

        // ---- batched probes: 4 independent loads, collapse to a 4-bit mask ----
        int pvm;
        {
            const float* xq = x + ((size_t)b0 * N_ + t64) * 16;
            const float4 p0 = *(const float4*)(xq);
            const float4 p1 = *(const float4*)(xq + (size_t)N_ * 16);
            const float4 p2 = *(const float4*)(xq + (size_t)N_ * 32);
            const float4 p3 = *(const float4*)(xq + (size_t)N_ * 48);
            const int v0 = !(p0.x == PADV && p0.y == PADV && p0.z == PADV && p0.w == PADV);
            const int v1 = !(p1.x == PADV && p1.y == PADV && p1.z == PADV && p1.w == PADV);
            const int v2 = !(p2.x == PADV && p2.y == PADV && p2.z == PADV && p2.w == PADV);
            const int v3 = !(p3.x == PADV && p3.y == PADV && p3.z == PADV && p3.w == PADV);
            pvm = v0 | (v1 << 1) | (v2 << 2) | (v3 << 3);
        }

        #pragma unroll 1
        for (int k = 0; k < 4; ++k) {
            if (!((pvm >> k) & 1)) continue;        // whole 64-pt tile is pad
            const int b = b0 + k;
            const float* xr = x + ((size_t)b * N_ + t64) * 16;

            // ---- x loads: 2 rows x 8 floats per lane ----
            const float* xp = xr + l31 * 16 + 8 * q;
            float4 a0 = ((const float4*)xp)[0];
            float4 a1 = ((const float4*)xp)[1];
            float4 c0 = ((const float4*)(xp + 512))[0];   // +32 rows
            float4 c1 = ((const float4*)(xp + 512))[1];

            // ---- W0 A-frags, re-loaded per tile (4 KB, L2-hot; transient) ----
            f16x8 w0f[4];
            #pragma unroll
            for (int c = 0; c < 4; ++c)
                w0f[c] = *(const f16x8*)(wtbuf + (32 * c + l31) * 16 + 8 * q);

            bool vA = (a0.x != PADV) || (a0.y != PADV) || (a0.z != PADV) || (a0.w != PADV) ||
                      (a1.x != PADV) || (a1.y != PADV) || (a1.z != PADV) || (a1.w != PADV);
            bool vB = (c0.x != PADV) || (c0.y != PADV) || (c0.z != PADV) || (c0.w != PADV) ||
                      (c1.x != PADV) || (c1.y != PADV) || (c1.z != PADV) || (c1.w != PADV);
            unsigned long long blA = __ballot(vA), blB = __ballot(vB);
            const unsigned mskA = (unsigned)blA | (unsigned)(blA >> 32);
            const unsigned mskB = (unsigned)blB | (unsigned)(blB >> 32);

            // ---- layer-0 B-frags (k = 8q+j natural order) ----
            F16x8 hf[2][8];
            hf[0][0].h2[0] = pkrtz(a0.x, a0.y);
            hf[0][0].h2[1] = pkrtz(a0.z, a0.w);
            hf[0][0].h2[2] = pkrtz(a1.x, a1.y);
            hf[0][0].h2[3] = pkrtz(a1.z, a1.w);
            hf[1][0].h2[0] = pkrtz(c0.x, c0.y);
            hf[1][0].h2[1] = pkrtz(c0.z, c0.w);
            hf[1][0].h2[2] = pkrtz(c1.x, c1.y);
            hf[1][0].h2[3] = pkrtz(c1.z, c1.w);

            f32x16 acc[2][4];

            // ---- L0: D[ch][pt], K=16 ----
            INIT_ACC_BIAS(pb0);
            #pragma unroll
            for (int c = 0; c < 4; ++c) {
                acc[0][c] = __builtin_amdgcn_mfma_f32_32x32x16_f16(w0f[c], hf[0][0].v, acc[0][c], 0, 0, 0);
                acc[1][c] = __builtin_amdgcn_mfma_f32_32x32x16_f16(w0f[c], hf[1][0].v, acc[1][c], 0, 0, 0);
            }
            EPILOGUE();

            // ---- L1: A = W1 from wA ----
            INIT_ACC_BIAS(pb1);
            #pragma unroll
            for (int s = 0; s < 8; ++s) {
                f16x8 wf[4];
                #pragma unroll
                for (int c = 0; c < 4; ++c)
                    wf[c] = *(const f16x8*)(wA + swz(32 * c + l31, 2 * s + q));
                #pragma unroll
                for (int c = 0; c < 4; ++c) {
                    acc[0][c] = __builtin_amdgcn_mfma_f32_32x32x16_f16(wf[c], hf[0][s].v, acc[0][c], 0, 0, 0);
                    acc[1][c] = __builtin_amdgcn_mfma_f32_32x32x16_f16(wf[c], hf[1][s].v, acc[1][c], 0, 0, 0);
                }
            }
            EPILOGUE();

            // ---- L2: A = W2 from wB ----
            INIT_ACC_BIAS(pb2);
            #pragma unroll
            for (int s = 0; s < 8; ++s) {
                f16x8 wf[4];
                #pragma unroll
                for (int c = 0; c < 4; ++c)
                    wf[c] = *(const f16x8*)(wB + swz(32 * c + l31, 2 * s + q));
                #pragma unroll
                for (int c = 0; c < 4; ++c) {
                    acc[0][c] = __builtin_amdgcn_mfma_f32_32x32x16_f16(wf[c], hf[0][s].v, acc[0][c], 0, 0, 0);
                    acc[1][c] = __builtin_amdgcn_mfma_f32_32x32x16_f16(wf[c], hf[1][s].v, acc[1][c], 0, 0, 0);
                }
            }
            EPILOGUE();

            // ---- L3: swapped orientation D[pt][ch]; b3 broadcast along rows ----
            {
                float bl3[4];
                #pragma unroll
                for (int c = 0; c < 4; ++c) bl3[c] = pb3[32 * c + l31];  // transient
                #pragma unroll
                for (int t = 0; t < 2; ++t)
                    #pragma unroll
                    for (int c = 0; c < 4; ++c)
                        #pragma unroll
                        for (int r = 0; r < 16; ++r) acc[t][c][r] = bl3[c];
            }
            #pragma unroll
            for (int s = 0; s < 8; ++s) {
                f16x8 wf[4];
                #pragma unroll
                for (int c = 0; c < 4; ++c)
                    wf[c] = *(const f16x8*)(wC + swz(32 * c + l31, 2 * s + q));
                #pragma unroll
                for (int c = 0; c < 4; ++c) {
                    acc[0][c] = __builtin_amdgcn_mfma_f32_32x32x16_f16(hf[0][s].v, wf[c], acc[0][c], 0, 0, 0);
                    acc[1][c] = __builtin_amdgcn_mfma_f32_32x32x16_f16(hf[1][s].v, wf[c], acc[1][c], 0, 0, 0);
                }
            }

            // ---- pool: lane owns ch = 32c + l31; rows are pts; masked select ----
            #pragma unroll
            for (int c = 0; c < 4; ++c) {
                float s0 = 0.f;
                #pragma unroll
                for (int t = 0; t < 2; ++t) {
                    const unsigned msk = t ? mskB : mskA;
                    #pragma unroll
                    for (int r = 0; r < 16; ++r) {
                        const int ptl = 4 * q + (r & 3) + 8 * (r >> 2);
                        float v = fmaxf(acc[t][c][r], 0.f);
                        s0 += ((msk >> ptl) & 1u) ? v : 0.f;   // select, NaN-safe
                    }
                }
                s0 += __shfl_xor(s0, 32);
                if (q == 0) atomicAdd(&pooled[b * 128 + 32 * c + l31], s0);
            }
        }
        // ---- wave-uniform pop: lane 0 increments, broadcast to all lanes ----
        unsigned mn = 0;
        if (lane == 0) mn = atomicAdd(cp, 1u);
        m = (unsigned)__builtin_amdgcn_readfirstlane((int)mn);
        if (m >= 512u) break;
    }
}

// ---- rho: fp32 MLP on pooled [512][128] -> out [512] ----
__global__ __launch_bounds__(128) void rho_kernel(
    const float* __restrict__ pooled,
    const float* __restrict__ w0, const float* __restrict__ b0,
    const float* __restrict__ w1, const float* __restrict__ b1,
    const float* __restrict__ w2, const float* __restrict__ b2,
    const float* __restrict__ w3, const float* __restrict__ b3,
    float* __restrict__ out)
{
    __shared__ float buf[2][128];
    __shared__ float red[2];
    const int b = blockIdx.x, t = threadIdx.x;
    buf[0][t] = pooled[b * 128 + t];
    __syncthreads();
    const float* ws3[3] = {w0, w1, w2};
    const float* bs3[3] = {b0, b1, b2};
    int cur = 0;
    #pragma unroll 1
    for (int l = 0; l < 3; ++l) {
        float acc = bs3[l][t];
        const float* w = ws3[l];
        #pragma unroll 8
        for (int k = 0; k < 128; ++k)
            acc = fmaf(buf[cur][k], w[k * 128 + t], acc);
        buf[cur ^ 1][t] = fmaxf(acc, 0.f);
        cur ^= 1;
        __syncthreads();
    }
    float v = buf[cur][t] * w3[t];
    #pragma unroll
    for (int off = 32; off > 0; off >>= 1)
        v += __shfl_down(v, off, 64);
    if ((t & 63) == 0) red[t >> 6] = v;
    __syncthreads();
    if (t == 0) out[b] = red[0] + red[1] + b3[0];
}

extern "C" void kernel_launch(void* const* d_in, const int* in_sizes, int n_in,
                              void* d_out, int out_size, void* d_ws, size_t ws_size,
                              hipStream_t stream)
{
    (void)in_sizes; (void)n_in; (void)out_size; (void)ws_size;
    const float* x      = (const float*)d_in[0];
    const float* phi_w0 = (const float*)d_in[1];
    const float* phi_b0 = (const float*)d_in[2];
    const float* phi_w1 = (const float*)d_in[3];
    const float* phi_b1 = (const float*)d_in[4];
    const float* phi_w2 = (const float*)d_in[5];
    const float* phi_b2 = (const float*)d_in[6];
    const float* phi_w3 = (const float*)d_in[7];
    const float* phi_b3 = (const float*)d_in[8];
    const float* rho_w0 = (const float*)d_in[9];
    const float* rho_b0 = (const float*)d_in[10];
    const float* rho_w1 = (const float*)d_in[11];
    const float* rho_b1 = (const float*)d_in[12];
    const float* rho_w2 = (const float*)d_in[13];
    const float* rho_b2 = (const float*)d_in[14];
    const float* rho_w3 = (const float*)d_in[15];
    const float* rho_b3 = (const float*)d_in[16];

    float*    pooled = (float*)d_ws;                        // 512*128*4 = 262144 B
    f16*      wtbuf  = (f16*)((char*)d_ws + 262144);        // 51200 f16 = 102400 B
    unsigned* cnt    = (unsigned*)((char*)d_ws + 364544);   // 8 * 4 B work counters

    static int smem_set = 0;
    if (!smem_set) {
        hipFuncSetAttribute((const void*)phi_pool_kernel,
                            hipFuncAttributeMaxDynamicSharedMemorySize, 98304);
        smem_set = 1;
    }

    prep_kernel<<<256, 256, 0, stream>>>(phi_w0, phi_w1, phi_w2, phi_w3, wtbuf, pooled, cnt);
    phi_pool_kernel<<<256, 512, 98304, stream>>>(x, wtbuf, phi_b0, phi_b1, phi_b2, phi_b3,
                                                 pooled, cnt);
    rho_kernel<<<B_, 128, 0, stream>>>(pooled, rho_w0, rho_b0, rho_w1, rho_b1,
                                       rho_w2, rho_b2, rho_w3, rho_b3, (float*)d_out);
}

// Round 17
// 199.270 us; speedup vs baseline: 1.4393x; 1.0072x over previous
//
#include <hip/hip_runtime.h>

typedef _Float16 f16;
typedef f16  f16x2  __attribute__((ext_vector_type(2)));
typedef f16  f16x8  __attribute__((ext_vector_type(8)));
typedef __fp16 h16x2 __attribute__((ext_vector_type(2)));
typedef float f32x16 __attribute__((ext_vector_type(16)));

#define B_   512
#define N_   2048
#define PADV -10000.0f

union F16x8 { f16x8 v; f16x2 h2[4]; };

__device__ __forceinline__ f16x2 pkrtz(float a, float b) {
    h16x2 r = __builtin_amdgcn_cvt_pkrtz(a, b);
    return __builtin_bit_cast(f16x2, r);
}

// wtbuf layout (f16): W0t [128 out][16 in] at 0 (natural in-order)
// Wt1/Wt2/Wt3 [128 out][128 slot] at 2048/18432/34816, slot k permuted by sigma
// to match the MFMA D-register layout (D regs ARE the next layer's B-frag).
__global__ void prep_kernel(const float* __restrict__ w0, const float* __restrict__ w1,
                            const float* __restrict__ w2, const float* __restrict__ w3,
                            f16* __restrict__ out, float* __restrict__ pooled,
                            unsigned* __restrict__ cnt)
{
    int i = blockIdx.x * 256 + threadIdx.x;   // grid 256*256 = 65536
    if (i < 2048) {
        out[i] = (f16)w0[(i & 15) * 128 + (i >> 4)];
    } else if (i < 51200) {
        int j = i - 2048;
        int l = j >> 14, r = j & 16383;
        int o = r >> 7, slot = r & 127;
        int s = slot >> 4, qq = (slot >> 3) & 1, jj = slot & 7;
        int sig = 32 * (s >> 1) + 16 * (s & 1) + 4 * qq + 8 * (jj >> 2) + (jj & 3);
        const float* w = (l == 0) ? w1 : (l == 1) ? w2 : w3;
        out[i] = (f16)w[sig * 128 + o];
    }
    pooled[i] = 0.f;   // 512*128 = 65536
    // work counters: 8 slots, static chunks 0..255 pre-consumed
    if (blockIdx.x == 255 && threadIdx.x < 8) cnt[threadIdx.x] = 256u;
}

// swizzled byte offset into a [128 row][16 chunk] 16B-chunk weight tile
__device__ __forceinline__ int swz(int row, int chunk) {
    return row * 256 + ((chunk ^ (row & 15)) << 4);
}

__device__ __forceinline__ void gl_lds16(const void* g, void* l) {
    __builtin_amdgcn_global_load_lds(
        (const __attribute__((address_space(1))) void*)g,
        (__attribute__((address_space(3))) void*)l, 16, 0, 0);
}

// ---- fused phi (4 layers, f16 MFMA) + masked pool — resident-weight workers ----
// SESSION-BEST STRUCTURE (measured 3x: 201.6 / 200.8 / 200.7 us total; phi
// 78.8-97.9us band = +-10% run-to-run clock variance on identical binary):
// W1/W2/W3 in 96 KB dynamic LDS for the kernel lifetime (staged once, ONE
// barrier). Wave-slot wv pops chunks of 4 b's x 1 tile from cnt[wv]; first
// chunk static (=blockIdx). Batched probes. No barriers in the loop.
// Structural ceiling (why this plateaus at ~80us phi): t=2 body needs ~250
// regs -> 512-reg/lane file forces 2 waves/SIMD (4/SIMD => 128-reg cap =>
// spill, verified R2/R5/R7); per-tile chain ~3000cyc x ~33 tiles/CU / 2-way
// overlap ~= 80us. Neighbors measured worse: restage+barriers 103, t=1+
// barriers 92, static sched 86, t=1@3w/SIMD 166. Remaining levers <noise.
// R4: pop must be wave-uniform (lane 0 + readfirstlane).
// R8: dynamic stealing > static schedule; biases from GLOBAL beat bias-LDS.
__global__ __launch_bounds__(512, 2) void phi_pool_kernel(
    const float* __restrict__ x,
    const f16*  __restrict__ wtbuf,
    const float* __restrict__ pb0, const float* __restrict__ pb1,
    const float* __restrict__ pb2, const float* __restrict__ pb3,
    float* __restrict__ pooled, unsigned* __restrict__ cnt)
{
    extern __shared__ char smem[];
    char* wA = smem;             // W1 32 KB swizzled
    char* wB = smem + 32768;     // W2
    char* wC = smem + 65536;     // W3

    const int tid  = threadIdx.x;
    const int lane = tid & 63;
    const int wv   = tid >> 6;          // 0..7
    const int l31  = lane & 31;
    const int q    = lane >> 5;

    // ---- stage W1/W2/W3 once: wave wv stages rows [16wv, 16wv+16) of each ----
    {
        const f16* wsrc = wtbuf + 2048;
        #pragma unroll
        for (int i = 0; i < 4; ++i) {
            const int row   = wv * 16 + i * 4 + (lane >> 4);
            const int chunk = (lane & 15) ^ (row & 15);
            const int loff  = (wv * 16 + i * 4) * 256;   // bytes, wave-uniform
            gl_lds16(wsrc +         row * 128 + chunk * 8, wA + loff);
            gl_lds16(wsrc + 16384 + row * 128 + chunk * 8, wB + loff);
            gl_lds16(wsrc + 32768 + row * 128 + chunk * 8, wC + loff);
        }
    }

    __syncthreads();   // staging drained; last barrier in the kernel

    // bias pre-load into accumulator: acc[t][c][4g+e] = bias[32c + 8g + 4q + e]
    #define INIT_ACC_BIAS(pb)                                              \
        {                                                                  \
            _Pragma("unroll")                                              \
            for (int c = 0; c < 4; ++c) {                                  \
                _Pragma("unroll")                                          \
                for (int g = 0; g < 4; ++g) {                              \
                    float4 bb = *(const float4*)((pb) + 32 * c + 8 * g + 4 * q); \
                    const float* bbp = (const float*)&bb;                  \
                    _Pragma("unroll")                                      \
                    for (int e = 0; e < 4; ++e) {                          \
                        acc[0][c][4 * g + e] = bbp[e];                     \
                        acc[1][c][4 * g + e] = bbp[e];                     \
                    }                                                      \
                }                                                          \
            }                                                              \
        }

    // epilogue: packed cvt + relu; D regs ARE the next B-frag (weights permuted)
    #define EPILOGUE()                                                     \
        {                                                                  \
            const f16x2 z2 = {(f16)0.f, (f16)0.f};                         \
            _Pragma("unroll")                                              \
            for (int t = 0; t < 2; ++t) {                                  \
                _Pragma("unroll")                                          \
                for (int s = 0; s < 8; ++s) {                              \
                    const int c = s >> 1, r0 = 8 * (s & 1);                \
                    _Pragma("unroll")                                      \
                    for (int p = 0; p < 4; ++p) {                          \
                        f16x2 mm = pkrtz(                                  \
                            acc[t][c][r0 + 2 * p], acc[t][c][r0 + 2 * p + 1]); \
                        hf[t][s].h2[p] = __builtin_elementwise_max(mm, z2); \
                    }                                                      \
                }                                                          \
            }                                                              \
        }

    unsigned m = blockIdx.x;            // static first chunk (0..255)
    unsigned* cp = cnt + wv;            // this wave-slot's counter

    #pragma unroll 1
    for (;;) {
        const int t64 = (int)(m & 31) << 6;        // tile point base (0..1984)
        const int db0 = (int)((m >> 5) << 2);      // 4 consecutive b's
        const int b0  = (wv << 6) + db0;

        // ---- batched probes: 4 independent loads, collapse to a 4-bit mask ----
        int pvm;
        {
            const float* xq = x + ((size_t)b0 * N_ + t64) * 16;
            const float4 p0 = *(const float4*)(xq);
            const float4 p1 = *(const float4*)(xq + (size_t)N_ * 16);
            const float4 p2 = *(const float4*)(xq + (size_t)N_ * 32);
            const float4 p3 = *(const float4*)(xq + (size_t)N_ * 48);
            const int v0 = !(p0.x == PADV && p0.y == PADV && p0.z == PADV && p0.w == PADV);
            const int v1 = !(p1.x == PADV && p1.y == PADV && p1.z == PADV && p1.w == PADV);
            const int v2 = !(p2.x == PADV && p2.y == PADV && p2.z == PADV && p2.w == PADV);
            const int v3 = !(p3.x == PADV && p3.y == PADV && p3.z == PADV && p3.w == PADV);
            pvm = v0 | (v1 << 1) | (v2 << 2) | (v3 << 3);
        }

        #pragma unroll 1
        for (int k = 0; k < 4; ++k) {
            if (!((pvm >> k) & 1)) continue;        // whole 64-pt tile is pad
            const int b = b0 + k;
            const float* xr = x + ((size_t)b * N_ + t64) * 16;

            // ---- x loads: 2 rows x 8 floats per lane ----
            const float* xp = xr + l31 * 16 + 8 * q;
            float4 a0 = ((const float4*)xp)[0];
            float4 a1 = ((const float4*)xp)[1];
            float4 c0 = ((const float4*)(xp + 512))[0];   // +32 rows
            float4 c1 = ((const float4*)(xp + 512))[1];

            // ---- W0 A-frags, re-loaded per tile (4 KB, L2-hot; transient) ----
            f16x8 w0f[4];
            #pragma unroll
            for (int c = 0; c < 4; ++c)
                w0f[c] = *(const f16x8*)(wtbuf + (32 * c + l31) * 16 + 8 * q);

            bool vA = (a0.x != PADV) || (a0.y != PADV) || (a0.z != PADV) || (a0.w != PADV) ||
                      (a1.x != PADV) || (a1.y != PADV) || (a1.z != PADV) || (a1.w != PADV);
            bool vB = (c0.x != PADV) || (c0.y != PADV) || (c0.z != PADV) || (c0.w != PADV) ||
                      (c1.x != PADV) || (c1.y != PADV) || (c1.z != PADV) || (c1.w != PADV);
            unsigned long long blA = __ballot(vA), blB = __ballot(vB);
            const unsigned mskA = (unsigned)blA | (unsigned)(blA >> 32);
            const unsigned mskB = (unsigned)blB | (unsigned)(blB >> 32);

            // ---- layer-0 B-frags (k = 8q+j natural order) ----
            F16x8 hf[2][8];
            hf[0][0].h2[0] = pkrtz(a0.x, a0.y);
            hf[0][0].h2[1] = pkrtz(a0.z, a0.w);
            hf[0][0].h2[2] = pkrtz(a1.x, a1.y);
            hf[0][0].h2[3] = pkrtz(a1.z, a1.w);
            hf[1][0].h2[0] = pkrtz(c0.x, c0.y);
            hf[1][0].h2[1] = pkrtz(c0.z, c0.w);
            hf[1][0].h2[2] = pkrtz(c1.x, c1.y);
            hf[1][0].h2[3] = pkrtz(c1.z, c1.w);

            f32x16 acc[2][4];

            // ---- L0: D[ch][pt], K=16 ----
            INIT_ACC_BIAS(pb0);
            #pragma unroll
            for (int c = 0; c < 4; ++c) {
                acc[0][c] = __builtin_amdgcn_mfma_f32_32x32x16_f16(w0f[c], hf[0][0].v, acc[0][c], 0, 0, 0);
                acc[1][c] = __builtin_amdgcn_mfma_f32_32x32x16_f16(w0f[c], hf[1][0].v, acc[1][c], 0, 0, 0);
            }
            EPILOGUE();

            // ---- L1: A = W1 from wA ----
            INIT_ACC_BIAS(pb1);
            #pragma unroll
            for (int s = 0; s < 8; ++s) {
                f16x8 wf[4];
                #pragma unroll
                for (int c = 0; c < 4; ++c)
                    wf[c] = *(const f16x8*)(wA + swz(32 * c + l31, 2 * s + q));
                #pragma unroll
                for (int c = 0; c < 4; ++c) {
                    acc[0][c] = __builtin_amdgcn_mfma_f32_32x32x16_f16(wf[c], hf[0][s].v, acc[0][c], 0, 0, 0);
                    acc[1][c] = __builtin_amdgcn_mfma_f32_32x32x16_f16(wf[c], hf[1][s].v, acc[1][c], 0, 0, 0);
                }
            }
            EPILOGUE();

            // ---- L2: A = W2 from wB ----
            INIT_ACC_BIAS(pb2);
            #pragma unroll
            for (int s = 0; s < 8; ++s) {
                f16x8 wf[4];
                #pragma unroll
                for (int c = 0; c < 4; ++c)
                    wf[c] = *(const f16x8*)(wB + swz(32 * c + l31, 2 * s + q));
                #pragma unroll
                for (int c = 0; c < 4; ++c) {
                    acc[0][c] = __builtin_amdgcn_mfma_f32_32x32x16_f16(wf[c], hf[0][s].v, acc[0][c], 0, 0, 0);
                    acc[1][c] = __builtin_amdgcn_mfma_f32_32x32x16_f16(wf[c], hf[1][s].v, acc[1][c], 0, 0, 0);
                }
            }
            EPILOGUE();

            // ---- L3: swapped orientation D[pt][ch]; b3 broadcast along rows ----
            {
                float bl3[4];
                #pragma unroll
                for (int c = 0; c < 4; ++c) bl3[c] = pb3[32 * c + l31];  // transient
                #pragma unroll
                for (int t = 0; t < 2; ++t)
                    #pragma unroll
                    for (int c = 0; c < 4; ++c)
                        #pragma unroll
                        for (int r = 0; r < 16; ++r) acc[t][c][r] = bl3[c];
            }
            #pragma unroll
            for (int s = 0; s < 8; ++s) {
                f16x8 wf[4];
                #pragma unroll
                for (int c = 0; c < 4; ++c)
                    wf[c] = *(const f16x8*)(wC + swz(32 * c + l31, 2 * s + q));
                #pragma unroll
                for (int c = 0; c < 4; ++c) {
                    acc[0][c] = __builtin_amdgcn_mfma_f32_32x32x16_f16(hf[0][s].v, wf[c], acc[0][c], 0, 0, 0);
                    acc[1][c] = __builtin_amdgcn_mfma_f32_32x32x16_f16(hf[1][s].v, wf[c], acc[1][c], 0, 0, 0);
                }
            }

            // ---- pool: lane owns ch = 32c + l31; rows are pts; masked select ----
            #pragma unroll
            for (int c = 0; c < 4; ++c) {
                float s0 = 0.f;
                #pragma unroll
                for (int t = 0; t < 2; ++t) {
                    const unsigned msk = t ? mskB : mskA;
                    #pragma unroll
                    for (int r = 0; r < 16; ++r) {
                        const int ptl = 4 * q + (r & 3) + 8 * (r >> 2);
                        float v = fmaxf(acc[t][c][r], 0.f);
                        s0 += ((msk >> ptl) & 1u) ? v : 0.f;   // select, NaN-safe
                    }
                }
                s0 += __shfl_xor(s0, 32);
                if (q == 0) atomicAdd(&pooled[b * 128 + 32 * c + l31], s0);
            }
        }
        // ---- wave-uniform pop: lane 0 increments, broadcast to all lanes ----
        unsigned mn = 0;
        if (lane == 0) mn = atomicAdd(cp, 1u);
        m = (unsigned)__builtin_amdgcn_readfirstlane((int)mn);
        if (m >= 512u) break;
    }
}

// ---- rho: fp32 MLP on pooled [512][128] -> out [512] ----
__global__ __launch_bounds__(128) void rho_kernel(
    const float* __restrict__ pooled,
    const float* __restrict__ w0, const float* __restrict__ b0,
    const float* __restrict__ w1, const float* __restrict__ b1,
    const float* __restrict__ w2, const float* __restrict__ b2,
    const float* __restrict__ w3, const float* __restrict__ b3,
    float* __restrict__ out)
{
    __shared__ float buf[2][128];
    __shared__ float red[2];
    const int b = blockIdx.x, t = threadIdx.x;
    buf[0][t] = pooled[b * 128 + t];
    __syncthreads();
    const float* ws3[3] = {w0, w1, w2};
    const float* bs3[3] = {b0, b1, b2};
    int cur = 0;
    #pragma unroll 1
    for (int l = 0; l < 3; ++l) {
        float acc = bs3[l][t];
        const float* w = ws3[l];
        #pragma unroll 8
        for (int k = 0; k < 128; ++k)
            acc = fmaf(buf[cur][k], w[k * 128 + t], acc);
        buf[cur ^ 1][t] = fmaxf(acc, 0.f);
        cur ^= 1;
        __syncthreads();
    }
    float v = buf[cur][t] * w3[t];
    #pragma unroll
    for (int off = 32; off > 0; off >>= 1)
        v += __shfl_down(v, off, 64);
    if ((t & 63) == 0) red[t >> 6] = v;
    __syncthreads();
    if (t == 0) out[b] = red[0] + red[1] + b3[0];
}

extern "C" void kernel_launch(void* const* d_in, const int* in_sizes, int n_in,
                              void* d_out, int out_size, void* d_ws, size_t ws_size,
                              hipStream_t stream)
{
    (void)in_sizes; (void)n_in; (void)out_size; (void)ws_size;
    const float* x      = (const float*)d_in[0];
    const float* phi_w0 = (const float*)d_in[1];
    const float* phi_b0 = (const float*)d_in[2];
    const float* phi_w1 = (const float*)d_in[3];
    const float* phi_b1 = (const float*)d_in[4];
    const float* phi_w2 = (const float*)d_in[5];
    const float* phi_b2 = (const float*)d_in[6];
    const float* phi_w3 = (const float*)d_in[7];
    const float* phi_b3 = (const float*)d_in[8];
    const float* rho_w0 = (const float*)d_in[9];
    const float* rho_b0 = (const float*)d_in[10];
    const float* rho_w1 = (const float*)d_in[11];
    const float* rho_b1 = (const float*)d_in[12];
    const float* rho_w2 = (const float*)d_in[13];
    const float* rho_b2 = (const float*)d_in[14];
    const float* rho_w3 = (const float*)d_in[15];
    const float* rho_b3 = (const float*)d_in[16];

    float*    pooled = (float*)d_ws;                        // 512*128*4 = 262144 B
    f16*      wtbuf  = (f16*)((char*)d_ws + 262144);        // 51200 f16 = 102400 B
    unsigned* cnt    = (unsigned*)((char*)d_ws + 364544);   // 8 * 4 B work counters

    static int smem_set = 0;
    if (!smem_set) {
        hipFuncSetAttribute((const void*)phi_pool_kernel,
                            hipFuncAttributeMaxDynamicSharedMemorySize, 98304);
        smem_set = 1;
    }

    prep_kernel<<<256, 256, 0, stream>>>(phi_w0, phi_w1, phi_w2, phi_w3, wtbuf, pooled, cnt);
    phi_pool_kernel<<<256, 512, 98304, stream>>>(x, wtbuf, phi_b0, phi_b1, phi_b2, phi_b3,
                                                 pooled, cnt);
    rho_kernel<<<B_, 128, 0, stream>>>(pooled, rho_w0, rho_b0, rho_w1, rho_b1,
                                       rho_w2, rho_b2, rho_w3, rho_b3, (float*)d_out);
}